// Round 8
// baseline (178.065 us; speedup 1.0000x reference)
//
#include <hip/hip_runtime.h>

#define HW_TOTAL (4096 * 4096)
#define NBINS 256
#define NCHUNK (HW_TOTAL / 4)      // int4 chunks = 4M
#define GRID_B 512                 // 2 blocks/CU, co-resident (VGPR<=64 enforced)
#define BLK 1024                   // 16 waves
#define BATCH 8                    // int4 chunks per thread
// 512 blocks * 1024 threads * 8 chunks = 4M chunks exactly.
#define DES (GRID_B - 1)           // designated threshold-computing block

typedef int int4n __attribute__((ext_vector_type(4)));               // aligned 16
typedef int int4a __attribute__((ext_vector_type(4), aligned(4)));   // dword-aligned

// ws (u32 words): [0..511] per-block done flags; [512] bcast (= thresh+1);
// words [1024 ..) : partials[GRID_B][NBINS]. First 4 KiB memset each call.
#define WS_PART_OFF 1024
#define WS_NEED (4096 + GRID_B * NBINS * 4)

// ---------------------------------------------------------------------------
// Fused single-dispatch Otsu, zero contended atomics.
// Phase A: LDS hist (4-bank-interleaved sub-hists) -> per-block partial store
// (plain) -> threadfence (L2 writeback) -> release flag.
// Block DES: spin-scan all flags, reduce partials, wave-scan + fp64 argmax,
// publish thresh+1 to bcast word. All blocks spin on bcast (value rides it).
// Phase C: binarize own chunk; unaligned dwordx4 loads realize the +1 output
// shift (out image lives at out[1..HW]); stores stay 16B-aligned nontemporal.
// ---------------------------------------------------------------------------
__global__ __launch_bounds__(BLK, 8) void otsu_fused_k(const int* __restrict__ img,
                                                       int* __restrict__ out,
                                                       unsigned* __restrict__ ws) {
    __shared__ unsigned h[4 * NBINS];
    __shared__ unsigned red[4][NBINS];
    __shared__ int s_thresh;

    const int t = threadIdx.x;
    const int b = blockIdx.x;
    const int4* img4 = (const int4*)img;

    for (int i = t; i < 4 * NBINS; i += BLK) h[i] = 0;
    __syncthreads();

    // ---------------- Phase A: histogram ----------------
    unsigned* hp = h + (t & 3);            // 4-bank-interleaved sub-hist base
    const int wave = t >> 6, lane = t & 63;
    const int i0 = b * (BLK * BATCH) + wave * (64 * BATCH) + lane;

    int4 v[BATCH];
#pragma unroll
    for (int k = 0; k < BATCH; ++k) v[k] = img4[i0 + k * 64];
#pragma unroll
    for (int k = 0; k < BATCH; ++k) {
        atomicAdd(&hp[((unsigned)v[k].x) << 2], 1u);
        atomicAdd(&hp[((unsigned)v[k].y) << 2], 1u);
        atomicAdd(&hp[((unsigned)v[k].z) << 2], 1u);
        atomicAdd(&hp[((unsigned)v[k].w) << 2], 1u);
    }
    __syncthreads();

    if (t < NBINS) {
        unsigned s = h[t << 2] + h[(t << 2) | 1] + h[(t << 2) | 2] + h[(t << 2) | 3];
        ws[WS_PART_OFF + b * NBINS + t] = s;       // plain store, no contention
    }
    __syncthreads();                                // all partial stores drained
    if (t == 0) {
        __threadfence();                            // L2 writeback -> agent-visible
        __hip_atomic_store(&ws[b], 1u, __ATOMIC_RELEASE, __HIP_MEMORY_SCOPE_AGENT);
    }

    // ---------------- Designated block: threshold ----------------
    if (b == DES) {
        for (;;) {
            int ok = 1;
            if (t < GRID_B)
                ok = (__hip_atomic_load(&ws[t], __ATOMIC_RELAXED,
                                        __HIP_MEMORY_SCOPE_AGENT) != 0u);
            if (__syncthreads_and(ok)) break;
            __builtin_amdgcn_s_sleep(2);
        }
        __threadfence();

        // reduce 512 partial rows; thread (bin,q) sums 128 rows, 16-deep batch
        const unsigned* parts = ws + WS_PART_OFF;
        const int bin = t & 255, q = t >> 8;
        unsigned s = 0;
        for (int r = q * 128; r < q * 128 + 128; r += 16) {
#pragma unroll
            for (int k = 0; k < 16; ++k) s += parts[(r + k) * NBINS + bin];
        }
        red[q][bin] = s;
        __syncthreads();
        if (t < NBINS)
            h[t] = red[0][t] + red[1][t] + red[2][t] + red[3][t];  // reuse h as cnt
        __syncthreads();

        if (t < 64) {
            uint4 c4 = ((const uint4*)h)[t];
            unsigned cs[4] = {c4.x, c4.y, c4.z, c4.w};

            unsigned long long lc[4], lv[4];
            unsigned long long ccum = 0ull, vcum = 0ull;
#pragma unroll
            for (int k = 0; k < 4; ++k) {
                ccum += cs[k];
                vcum += (unsigned long long)cs[k] * (unsigned)(4 * t + k);
                lc[k] = ccum;
                lv[k] = vcum;
            }
            unsigned long long cscan = ccum, vscan = vcum;
            for (int d = 1; d < 64; d <<= 1) {
                unsigned long long cu = __shfl_up(cscan, d);
                unsigned long long vu = __shfl_up(vscan, d);
                if (t >= d) { cscan += cu; vscan += vu; }
            }
            const unsigned long long cbase = cscan - ccum;
            const unsigned long long vbase = vscan - vcum;
            const unsigned long long vtotal = __shfl(vscan, 63);

            double best = -1.0;
            int bestt = 255;
            const double hw = (double)HW_TOTAL;
            const double vtot_d = (double)vtotal;
#pragma unroll
            for (int k = 0; k < 4; ++k) {
                int tt = 4 * t + k;
                if (tt > 254) continue;
                double nb = (double)(cbase + lc[k]);
                double sb = (double)(vbase + lv[k]);
                double nw = hw - nb;
                double sw = vtot_d - sb;
                double dm = sb / nb - sw / nw;
                double var = nb * nw * dm * dm;
                if (var > best || (var == best && tt < bestt)) { best = var; bestt = tt; }
            }
            for (int d = 32; d >= 1; d >>= 1) {
                double ov = __shfl_xor(best, d);
                int ot = __shfl_xor(bestt, d);
                if (ov > best || (ov == best && ot < bestt)) { best = ov; bestt = ot; }
            }
            if (t == 0) {
                out[0] = bestt;
                __hip_atomic_store(&ws[GRID_B], (unsigned)bestt + 1u,
                                   __ATOMIC_RELEASE, __HIP_MEMORY_SCOPE_AGENT);
            }
        }
    }

    // ---------------- All blocks: wait for published threshold ----------------
    if (t == 0) {
        unsigned f;
        while ((f = __hip_atomic_load(&ws[GRID_B], __ATOMIC_ACQUIRE,
                                      __HIP_MEMORY_SCOPE_AGENT)) == 0u)
            __builtin_amdgcn_s_sleep(2);
        s_thresh = (int)f - 1;
    }
    __syncthreads();
    const int thresh = s_thresh;

    // ---------------- Phase C: binarize own chunk ----------------
#pragma unroll
    for (int k = 0; k < BATCH; ++k) {
        const int c = i0 + k * 64;
        int4a pv = *(const int4a*)(img + (c ? 4 * c - 1 : 0));  // pixels 4c-1..4c+2
        int4n o;
        o.x = (pv.x <= thresh) ? 0 : 256;
        o.y = (pv.y <= thresh) ? 0 : 256;
        o.z = (pv.z <= thresh) ? 0 : 256;
        o.w = (pv.w <= thresh) ? 0 : 256;
        if (c == 0) { o.w = o.z; o.z = o.y; o.y = o.x; o.x = thresh; }
        __builtin_nontemporal_store(o, (int4n*)out + c);
    }
    if (i0 == 0)
        out[HW_TOTAL] = (img[HW_TOTAL - 1] <= thresh) ? 0 : 256;
}

// ---------------------------------------------------------------------------
// Fallback (ws too small — not expected; ws is 256 MB): 3-dispatch scheme.
// ---------------------------------------------------------------------------
__global__ __launch_bounds__(BLK, 8) void fb_hist_k(const int4* __restrict__ img4,
                                                    unsigned* __restrict__ ghist) {
    __shared__ unsigned h[4 * NBINS];
    const int t = threadIdx.x;
    for (int i = t; i < 4 * NBINS; i += BLK) h[i] = 0;
    __syncthreads();
    unsigned* hp = h + (t & 3);
    const int wave = t >> 6, lane = t & 63;
    const int i0 = blockIdx.x * (BLK * BATCH) + wave * (64 * BATCH) + lane;
    int4 v[BATCH];
#pragma unroll
    for (int k = 0; k < BATCH; ++k) v[k] = img4[i0 + k * 64];
#pragma unroll
    for (int k = 0; k < BATCH; ++k) {
        atomicAdd(&hp[((unsigned)v[k].x) << 2], 1u);
        atomicAdd(&hp[((unsigned)v[k].y) << 2], 1u);
        atomicAdd(&hp[((unsigned)v[k].z) << 2], 1u);
        atomicAdd(&hp[((unsigned)v[k].w) << 2], 1u);
    }
    __syncthreads();
    if (t < NBINS) {
        unsigned s = h[t << 2] + h[(t << 2) | 1] + h[(t << 2) | 2] + h[(t << 2) | 3];
        if (s) atomicAdd(&ghist[t], s);
    }
}

__global__ __launch_bounds__(64) void fb_thresh_k(const unsigned* __restrict__ cnt,
                                                  int* __restrict__ d_out,
                                                  unsigned* __restrict__ ws) {
    const int lane = threadIdx.x;
    uint4 c4 = ((const uint4*)cnt)[lane];
    unsigned cs[4] = {c4.x, c4.y, c4.z, c4.w};
    unsigned long long lc[4], lv[4], ccum = 0ull, vcum = 0ull;
#pragma unroll
    for (int k = 0; k < 4; ++k) {
        ccum += cs[k];
        vcum += (unsigned long long)cs[k] * (unsigned)(4 * lane + k);
        lc[k] = ccum; lv[k] = vcum;
    }
    unsigned long long cscan = ccum, vscan = vcum;
    for (int d = 1; d < 64; d <<= 1) {
        unsigned long long cu = __shfl_up(cscan, d);
        unsigned long long vu = __shfl_up(vscan, d);
        if (lane >= d) { cscan += cu; vscan += vu; }
    }
    const unsigned long long cbase = cscan - ccum, vbase = vscan - vcum;
    const unsigned long long vtotal = __shfl(vscan, 63);
    double best = -1.0; int bestt = 255;
#pragma unroll
    for (int k = 0; k < 4; ++k) {
        int tt = 4 * lane + k;
        if (tt > 254) continue;
        double nb = (double)(cbase + lc[k]), sb = (double)(vbase + lv[k]);
        double nw = (double)HW_TOTAL - nb, sw = (double)vtotal - sb;
        double dm = sb / nb - sw / nw;
        double var = nb * nw * dm * dm;
        if (var > best || (var == best && tt < bestt)) { best = var; bestt = tt; }
    }
    for (int d = 32; d >= 1; d >>= 1) {
        double ov = __shfl_xor(best, d);
        int ot = __shfl_xor(bestt, d);
        if (ov > best || (ov == best && ot < bestt)) { best = ov; bestt = ot; }
    }
    if (lane == 0) { d_out[0] = bestt; ws[GRID_B] = (unsigned)bestt + 1u; }
}

__global__ __launch_bounds__(BLK, 8) void fb_bin_k(const int* __restrict__ img,
                                                   int* __restrict__ out,
                                                   const unsigned* __restrict__ ws) {
    const int thresh = (int)ws[GRID_B] - 1;
    const int t = threadIdx.x;
    const int wave = t >> 6, lane = t & 63;
    const int i0 = blockIdx.x * (BLK * BATCH) + wave * (64 * BATCH) + lane;
#pragma unroll
    for (int k = 0; k < BATCH; ++k) {
        const int c = i0 + k * 64;
        int4a pv = *(const int4a*)(img + (c ? 4 * c - 1 : 0));
        int4n o;
        o.x = (pv.x <= thresh) ? 0 : 256;
        o.y = (pv.y <= thresh) ? 0 : 256;
        o.z = (pv.z <= thresh) ? 0 : 256;
        o.w = (pv.w <= thresh) ? 0 : 256;
        if (c == 0) { o.w = o.z; o.z = o.y; o.y = o.x; o.x = thresh; }
        __builtin_nontemporal_store(o, (int4n*)out + c);
    }
    if (i0 == 0)
        out[HW_TOTAL] = (img[HW_TOTAL - 1] <= thresh) ? 0 : 256;
}

extern "C" void kernel_launch(void* const* d_in, const int* in_sizes, int n_in,
                              void* d_out, int out_size, void* d_ws, size_t ws_size,
                              hipStream_t stream) {
    const int* img = (const int*)d_in[0];
    int* out = (int*)d_out;
    unsigned* ws = (unsigned*)d_ws;

    // zero flags + bcast (+ fallback ghist) every call
    (void)hipMemsetAsync(ws, 0, 4096, stream);

    if (ws_size >= (size_t)WS_NEED) {
        otsu_fused_k<<<GRID_B, BLK, 0, stream>>>(img, out, ws);
    } else {
        fb_hist_k<<<GRID_B, BLK, 0, stream>>>((const int4*)img, ws);
        fb_thresh_k<<<1, 64, 0, stream>>>(ws, out, ws);
        fb_bin_k<<<GRID_B, BLK, 0, stream>>>(img, out, ws);
    }
}

// Round 9
// 49.405 us; speedup vs baseline: 3.6042x; 3.6042x over previous
//
#include <hip/hip_runtime.h>

#define HW_TOTAL (4096 * 4096)
#define NBINS 256
#define NCHUNK (HW_TOTAL / 4)      // int4 chunks = 4M
#define GRID_B 512                 // 2 blocks/CU
#define BLK 1024                   // 16 waves
#define BATCH 8                    // int4 chunks per thread
// 512 blocks * 1024 threads * 8 chunks = 4M chunks exactly.

typedef int int4n __attribute__((ext_vector_type(4)));               // aligned 16
typedef int int4a __attribute__((ext_vector_type(4), aligned(4)));   // dword-aligned

// ws: [0..255] ghist (u32). Memset 1 KiB per call.
#define WS_NEED (NBINS * 4)

// ---------------------------------------------------------------------------
// Otsu threshold from a 256-bin count histogram, computed by one wave (64
// lanes, lane = t). cnt lives in LDS. Exact uint64 prefix scan via shfl +
// fp64 inter-class variance argmax (val_sum[t] == t*cnt[t] exactly).
// Returns best threshold in every lane of the wave.
// ---------------------------------------------------------------------------
__device__ __forceinline__ int otsu_scan64(const unsigned* cnt, int lane) {
    uint4 c4 = ((const uint4*)cnt)[lane];
    unsigned cs[4] = {c4.x, c4.y, c4.z, c4.w};

    unsigned long long lc[4], lv[4];
    unsigned long long ccum = 0ull, vcum = 0ull;
#pragma unroll
    for (int k = 0; k < 4; ++k) {
        ccum += cs[k];
        vcum += (unsigned long long)cs[k] * (unsigned)(4 * lane + k);
        lc[k] = ccum;
        lv[k] = vcum;
    }
    unsigned long long cscan = ccum, vscan = vcum;
    for (int d = 1; d < 64; d <<= 1) {
        unsigned long long cu = __shfl_up(cscan, d);
        unsigned long long vu = __shfl_up(vscan, d);
        if (lane >= d) { cscan += cu; vscan += vu; }
    }
    const unsigned long long cbase = cscan - ccum;
    const unsigned long long vbase = vscan - vcum;
    const unsigned long long vtotal = __shfl(vscan, 63);

    double best = -1.0;
    int bestt = 255;
    const double hw = (double)HW_TOTAL;
    const double vtot_d = (double)vtotal;
#pragma unroll
    for (int k = 0; k < 4; ++k) {
        int tt = 4 * lane + k;
        if (tt > 254) continue;
        double nb = (double)(cbase + lc[k]);
        double sb = (double)(vbase + lv[k]);
        double nw = hw - nb;
        double sw = vtot_d - sb;
        double dm = sb / nb - sw / nw;
        double var = nb * nw * dm * dm;
        if (var > best || (var == best && tt < bestt)) { best = var; bestt = tt; }
    }
    for (int d = 32; d >= 1; d >>= 1) {
        double ov = __shfl_xor(best, d);
        int ot = __shfl_xor(bestt, d);
        if (ov > best || (ov == best && ot < bestt)) { best = ov; bestt = ot; }
    }
    return bestt;
}

// ---------------------------------------------------------------------------
// Kernel 1: histogram. 4-bank-interleaved LDS sub-hists h[(bin<<2)|sub],
// sub = t&3. One batch of 8 int4 loads per thread (8 in flight). Flush via
// device-scope atomicAdd into ghist (fire-and-forget, ~512-deep chains).
// ---------------------------------------------------------------------------
__global__ __launch_bounds__(BLK, 8) void otsu_hist_k(const int4* __restrict__ img4,
                                                      unsigned* __restrict__ ghist) {
    __shared__ unsigned h[4 * NBINS];
    const int t = threadIdx.x;
    for (int i = t; i < 4 * NBINS; i += BLK) h[i] = 0;
    __syncthreads();

    unsigned* hp = h + (t & 3);
    const int wave = t >> 6, lane = t & 63;
    const int i0 = blockIdx.x * (BLK * BATCH) + wave * (64 * BATCH) + lane;

    int4 v[BATCH];
#pragma unroll
    for (int k = 0; k < BATCH; ++k) v[k] = img4[i0 + k * 64];
#pragma unroll
    for (int k = 0; k < BATCH; ++k) {
        atomicAdd(&hp[((unsigned)v[k].x) << 2], 1u);
        atomicAdd(&hp[((unsigned)v[k].y) << 2], 1u);
        atomicAdd(&hp[((unsigned)v[k].z) << 2], 1u);
        atomicAdd(&hp[((unsigned)v[k].w) << 2], 1u);
    }
    __syncthreads();

    if (t < NBINS) {
        unsigned s = h[t << 2] + h[(t << 2) | 1] + h[(t << 2) | 2] + h[(t << 2) | 3];
        if (s) atomicAdd(&ghist[t], s);
    }
}

// ---------------------------------------------------------------------------
// Kernel 2: threshold + binarize in one dispatch. Every block redundantly
// computes the threshold from the 1 KiB ghist (wave 0, ~0.5 us, all blocks in
// parallel), LDS-broadcasts it, then binarizes its own chunk. Output image
// lives at out[1..HW]: unaligned dwordx4 loads (pixels 4c-1..4c+2) realize
// the +1 shift; stores stay 16 B-aligned nontemporal. Block 0's c==0 chunk
// writes out[0] = thresh; tail pixel handled by thread i0==0.
// ---------------------------------------------------------------------------
__global__ __launch_bounds__(BLK, 8) void otsu_bin_k(const int* __restrict__ img,
                                                     int* __restrict__ out,
                                                     const unsigned* __restrict__ ghist) {
    __shared__ unsigned cnt[NBINS];
    __shared__ int s_thresh;

    const int t = threadIdx.x;
    if (t < NBINS) cnt[t] = ghist[t];
    __syncthreads();
    if (t < 64) {
        int bt = otsu_scan64(cnt, t);
        if (t == 0) s_thresh = bt;
    }
    __syncthreads();
    const int thresh = s_thresh;

    const int wave = t >> 6, lane = t & 63;
    const int i0 = blockIdx.x * (BLK * BATCH) + wave * (64 * BATCH) + lane;
#pragma unroll
    for (int k = 0; k < BATCH; ++k) {
        const int c = i0 + k * 64;
        int4a pv = *(const int4a*)(img + (c ? 4 * c - 1 : 0));  // pixels 4c-1..4c+2
        int4n o;
        o.x = (pv.x <= thresh) ? 0 : 256;
        o.y = (pv.y <= thresh) ? 0 : 256;
        o.z = (pv.z <= thresh) ? 0 : 256;
        o.w = (pv.w <= thresh) ? 0 : 256;
        if (c == 0) { o.w = o.z; o.z = o.y; o.y = o.x; o.x = thresh; }
        __builtin_nontemporal_store(o, (int4n*)out + c);
    }
    if (i0 == 0)
        out[HW_TOTAL] = (img[HW_TOTAL - 1] <= thresh) ? 0 : 256;
}

extern "C" void kernel_launch(void* const* d_in, const int* in_sizes, int n_in,
                              void* d_out, int out_size, void* d_ws, size_t ws_size,
                              hipStream_t stream) {
    const int* img = (const int*)d_in[0];
    int* out = (int*)d_out;
    unsigned* ghist = (unsigned*)d_ws;

    (void)hipMemsetAsync(ghist, 0, WS_NEED, stream);   // zero ghist each call
    otsu_hist_k<<<GRID_B, BLK, 0, stream>>>((const int4*)img, ghist);
    otsu_bin_k<<<GRID_B, BLK, 0, stream>>>(img, out, ghist);
}

// Round 10
// 42.379 us; speedup vs baseline: 4.2017x; 1.1658x over previous
//
#include <hip/hip_runtime.h>

#define HW_TOTAL (4096 * 4096)
#define NBINS 256
#define NCHUNK (HW_TOTAL / 4)      // int4 chunks = 4M
#define NSUB 16                    // LDS sub-histograms

#define HGRID 256                  // hist blocks: 1/CU
#define HCPT 16                    // chunks per thread (2 halves of 8)
// 256 blocks * 1024 threads * 16 chunks = 4M exactly.

#define BGRID 512                  // bin blocks: 2/CU (R6-validated)
#define BBATCH 8
// 512 * 1024 * 8 = 4M exactly.

#define BLK 1024

typedef int int4n __attribute__((ext_vector_type(4)));               // aligned 16
typedef int int4a __attribute__((ext_vector_type(4), aligned(4)));   // dword-aligned

// ws layout: ws[0] = thresh; +256 B: partials[HGRID][NBINS] (u32)
#define WS_NEED (HGRID * NBINS * 4 + 256)

// ---------------------------------------------------------------------------
// Kernel 1: histogram. 16 LDS sub-histograms, layout h[sub*256 + bin]:
// bank = bin mod 32 -> all 32 banks in play, 64 random lanes ~= 2-way (free);
// 4 lanes/sub makes same-address collisions rare. Two 8-deep int4 batches
// keep 8 loads in flight. Flush: thread t sums h[ss*256+t] (conflict-free)
// and stores one partial row per block (no global atomics, no memset).
// ---------------------------------------------------------------------------
template <int MODE>
__global__ __launch_bounds__(BLK, 8) void otsu_hist_k(const int4* __restrict__ img4,
                                                      unsigned* __restrict__ out) {
    __shared__ unsigned h[NSUB * NBINS];    // 16 KiB
    const int t = threadIdx.x;
    for (int i = t; i < NSUB * NBINS; i += BLK) h[i] = 0;
    __syncthreads();

    unsigned* hp = h + ((t & (NSUB - 1)) << 8);   // sub-histogram base
    const int wave = t >> 6, lane = t & 63;
    const int i0 = blockIdx.x * (BLK * HCPT) + wave * (64 * HCPT) + lane;

#pragma unroll
    for (int half = 0; half < 2; ++half) {
        int4 v[8];
        const int j0 = i0 + half * (8 * 64);
#pragma unroll
        for (int k = 0; k < 8; ++k) v[k] = img4[j0 + k * 64];
#pragma unroll
        for (int k = 0; k < 8; ++k) {
            atomicAdd(&hp[(unsigned)v[k].x], 1u);
            atomicAdd(&hp[(unsigned)v[k].y], 1u);
            atomicAdd(&hp[(unsigned)v[k].z], 1u);
            atomicAdd(&hp[(unsigned)v[k].w], 1u);
        }
    }
    __syncthreads();

    if (t < NBINS) {
        unsigned s = 0;
#pragma unroll
        for (int ss = 0; ss < NSUB; ++ss) s += h[(ss << 8) | t];
        if (MODE == 0) {
            out[blockIdx.x * NBINS + t] = s;
        } else {
            if (s) atomicAdd(&out[t], s);
        }
    }
}

// ---------------------------------------------------------------------------
// Kernel 2: reduce B partial histograms + Otsu threshold. 1024 threads:
// thread (bin, q) sums its quarter of the rows with 16-deep batched loads.
// Wave 0 then does an exact uint64 prefix scan (shfl) + fp64 variance argmax.
// val_sum[t] == t * cnt[t] exactly, so only the count histogram is needed.
// ---------------------------------------------------------------------------
__global__ __launch_bounds__(1024) void otsu_thresh_k(const unsigned* __restrict__ partials,
                                                      int B,
                                                      int* __restrict__ d_out,
                                                      int* __restrict__ thresh_ws) {
    __shared__ unsigned red[4][NBINS];
    __shared__ unsigned cnt[NBINS];

    const int bin = threadIdx.x & 255;
    const int q = threadIdx.x >> 8;
    const int BQ = (B + 3) / 4;
    int r = q * BQ;
    const int e = min((q + 1) * BQ, B);
    unsigned s = 0;
    for (; r + 16 <= e; r += 16) {
#pragma unroll
        for (int k = 0; k < 16; ++k) s += partials[(r + k) * NBINS + bin];
    }
    for (; r < e; ++r) s += partials[r * NBINS + bin];
    red[q][bin] = s;
    __syncthreads();

    if (threadIdx.x < NBINS)
        cnt[bin] = red[0][bin] + red[1][bin] + red[2][bin] + red[3][bin];
    __syncthreads();

    if (threadIdx.x >= 64) return;
    const int lane = threadIdx.x;

    uint4 c4 = ((const uint4*)cnt)[lane];
    unsigned cs[4] = {c4.x, c4.y, c4.z, c4.w};

    unsigned long long lc[4], lv[4];
    unsigned long long ccum = 0ull, vcum = 0ull;
#pragma unroll
    for (int k = 0; k < 4; ++k) {
        ccum += cs[k];
        vcum += (unsigned long long)cs[k] * (unsigned)(4 * lane + k);
        lc[k] = ccum;
        lv[k] = vcum;
    }
    unsigned long long cscan = ccum, vscan = vcum;
    for (int d = 1; d < 64; d <<= 1) {
        unsigned long long cu = __shfl_up(cscan, d);
        unsigned long long vu = __shfl_up(vscan, d);
        if (lane >= d) { cscan += cu; vscan += vu; }
    }
    const unsigned long long cbase = cscan - ccum;
    const unsigned long long vbase = vscan - vcum;
    const unsigned long long vtotal = __shfl(vscan, 63);

    double best = -1.0;
    int bestt = 255;
    const double hw = (double)HW_TOTAL;
    const double vtot_d = (double)vtotal;
#pragma unroll
    for (int k = 0; k < 4; ++k) {
        int tt = 4 * lane + k;
        if (tt > 254) continue;
        double nb = (double)(cbase + lc[k]);
        double sb = (double)(vbase + lv[k]);
        double nw = hw - nb;
        double sw = vtot_d - sb;
        double dm = sb / nb - sw / nw;
        double var = nb * nw * dm * dm;
        if (var > best || (var == best && tt < bestt)) { best = var; bestt = tt; }
    }
    for (int d = 32; d >= 1; d >>= 1) {
        double ov = __shfl_xor(best, d);
        int ot = __shfl_xor(bestt, d);
        if (ov > best || (ov == best && ot < bestt)) { best = ov; bestt = ot; }
    }
    if (lane == 0) {
        d_out[0] = bestt;
        *thresh_ws = bestt;
    }
}

// ---------------------------------------------------------------------------
// Kernel 3: binarize (byte-identical to R6's validated version). Output image
// lives at out[1..HW]; aligned out-chunk out[4c..4c+3] needs pixels
// [4c-1..4c+2], loaded directly as a dword-aligned dwordx4 — no shuffles, no
// divergence. Reads are L3-hits (img staged by hist); 16 B-aligned nt stores.
// ---------------------------------------------------------------------------
__global__ __launch_bounds__(BLK, 8) void otsu_bin_k(const int* __restrict__ img,
                                                     int* __restrict__ out,
                                                     const int* __restrict__ thresh_ws) {
    const int thresh = *thresh_ws;     // uniform -> s_load
    const int t = threadIdx.x;
    const int wave = t >> 6, lane = t & 63;
    const int i0 = blockIdx.x * (BLK * BBATCH) + wave * (64 * BBATCH) + lane;

#pragma unroll
    for (int k = 0; k < BBATCH; ++k) {
        const int c = i0 + k * 64;
        const int4a* vp = (const int4a*)(img + (c ? 4 * c - 1 : 0));
        int4a v = *vp;                 // pixels 4c-1 .. 4c+2 (c>0)
        int4n o;
        o.x = (v.x <= thresh) ? 0 : 256;
        o.y = (v.y <= thresh) ? 0 : 256;
        o.z = (v.z <= thresh) ? 0 : 256;
        o.w = (v.w <= thresh) ? 0 : 256;
        if (c == 0) {                  // single thread: v = pixels 0..3
            o.w = o.z; o.z = o.y; o.y = o.x; o.x = thresh;
        }
        __builtin_nontemporal_store(o, (int4n*)out + c);
    }
    if (i0 == 0)
        out[HW_TOTAL] = (img[HW_TOTAL - 1] <= thresh) ? 0 : 256;
}

extern "C" void kernel_launch(void* const* d_in, const int* in_sizes, int n_in,
                              void* d_out, int out_size, void* d_ws, size_t ws_size,
                              hipStream_t stream) {
    const int* img = (const int*)d_in[0];
    int* out = (int*)d_out;
    int* thresh_ws = (int*)d_ws;
    unsigned* hist_buf = (unsigned*)((char*)d_ws + 256);

    if (ws_size >= (size_t)WS_NEED) {
        // partial-histogram scheme: no global atomics, no memset
        otsu_hist_k<0><<<HGRID, BLK, 0, stream>>>((const int4*)img, hist_buf);
        otsu_thresh_k<<<1, 1024, 0, stream>>>(hist_buf, HGRID, out, thresh_ws);
    } else {
        // fallback: atomic flush into a single 256-bin histogram
        (void)hipMemsetAsync(hist_buf, 0, NBINS * sizeof(unsigned), stream);
        otsu_hist_k<1><<<HGRID, BLK, 0, stream>>>((const int4*)img, hist_buf);
        otsu_thresh_k<<<1, 1024, 0, stream>>>(hist_buf, 1, out, thresh_ws);
    }
    otsu_bin_k<<<BGRID, BLK, 0, stream>>>(img, out, thresh_ws);
}

// Round 11
// 41.958 us; speedup vs baseline: 4.2439x; 1.0100x over previous
//
#include <hip/hip_runtime.h>

#define HW_TOTAL (4096 * 4096)
#define NBINS 256
#define NCHUNK (HW_TOTAL / 4)      // int4 chunks = 4M
#define NSUB 16                    // LDS sub-histograms

#define HGRID 256                  // hist blocks: 1/CU
#define HCPT 16                    // chunks per thread (2 halves of 8)
// 256 * 1024 * 16 = 4M exactly.

#define BGRID 512                  // bin blocks: 2/CU (R6-validated geometry)
#define BBATCH 8
// 512 * 1024 * 8 = 4M exactly.

#define BLK 1024

typedef int int4n __attribute__((ext_vector_type(4)));               // aligned 16
typedef int int4a __attribute__((ext_vector_type(4), aligned(4)));   // dword-aligned

// ws layout: +256 B: partials[HGRID][NBINS] (u32). (word 0 unused now.)
#define WS_NEED (HGRID * NBINS * 4 + 256)

// ---------------------------------------------------------------------------
// Otsu threshold from a 256-bin count histogram in LDS, one wave (lane = t).
// Exact uint64 prefix scan via shfl + fp64 inter-class variance argmax
// (val_sum[t] == t*cnt[t] exactly, so only the count histogram is needed).
// ---------------------------------------------------------------------------
__device__ __forceinline__ int otsu_scan64(const unsigned* cnt, int lane) {
    uint4 c4 = ((const uint4*)cnt)[lane];
    unsigned cs[4] = {c4.x, c4.y, c4.z, c4.w};

    unsigned long long lc[4], lv[4];
    unsigned long long ccum = 0ull, vcum = 0ull;
#pragma unroll
    for (int k = 0; k < 4; ++k) {
        ccum += cs[k];
        vcum += (unsigned long long)cs[k] * (unsigned)(4 * lane + k);
        lc[k] = ccum;
        lv[k] = vcum;
    }
    unsigned long long cscan = ccum, vscan = vcum;
    for (int d = 1; d < 64; d <<= 1) {
        unsigned long long cu = __shfl_up(cscan, d);
        unsigned long long vu = __shfl_up(vscan, d);
        if (lane >= d) { cscan += cu; vscan += vu; }
    }
    const unsigned long long cbase = cscan - ccum;
    const unsigned long long vbase = vscan - vcum;
    const unsigned long long vtotal = __shfl(vscan, 63);

    double best = -1.0;
    int bestt = 255;
    const double hw = (double)HW_TOTAL;
    const double vtot_d = (double)vtotal;
#pragma unroll
    for (int k = 0; k < 4; ++k) {
        int tt = 4 * lane + k;
        if (tt > 254) continue;
        double nb = (double)(cbase + lc[k]);
        double sb = (double)(vbase + lv[k]);
        double nw = hw - nb;
        double sw = vtot_d - sb;
        double dm = sb / nb - sw / nw;
        double var = nb * nw * dm * dm;
        if (var > best || (var == best && tt < bestt)) { best = var; bestt = tt; }
    }
    for (int d = 32; d >= 1; d >>= 1) {
        double ov = __shfl_xor(best, d);
        int ot = __shfl_xor(bestt, d);
        if (ov > best || (ov == best && ot < bestt)) { best = ov; bestt = ot; }
    }
    return bestt;
}

// ---------------------------------------------------------------------------
// Kernel 1 (unchanged from R10): histogram. 16 LDS sub-hists h[sub*256+bin]
// (bank = bin mod 32 -> all 32 banks, ~2-way = free). Two 8-deep int4
// batches. Flush: one partial row per block, conflict-free column sums.
// MODE 1: global atomic flush fallback.
// ---------------------------------------------------------------------------
template <int MODE>
__global__ __launch_bounds__(BLK, 8) void otsu_hist_k(const int4* __restrict__ img4,
                                                      unsigned* __restrict__ out) {
    __shared__ unsigned h[NSUB * NBINS];    // 16 KiB
    const int t = threadIdx.x;
    for (int i = t; i < NSUB * NBINS; i += BLK) h[i] = 0;
    __syncthreads();

    unsigned* hp = h + ((t & (NSUB - 1)) << 8);
    const int wave = t >> 6, lane = t & 63;
    const int i0 = blockIdx.x * (BLK * HCPT) + wave * (64 * HCPT) + lane;

#pragma unroll
    for (int half = 0; half < 2; ++half) {
        int4 v[8];
        const int j0 = i0 + half * (8 * 64);
#pragma unroll
        for (int k = 0; k < 8; ++k) v[k] = img4[j0 + k * 64];
#pragma unroll
        for (int k = 0; k < 8; ++k) {
            atomicAdd(&hp[(unsigned)v[k].x], 1u);
            atomicAdd(&hp[(unsigned)v[k].y], 1u);
            atomicAdd(&hp[(unsigned)v[k].z], 1u);
            atomicAdd(&hp[(unsigned)v[k].w], 1u);
        }
    }
    __syncthreads();

    if (t < NBINS) {
        unsigned s = 0;
#pragma unroll
        for (int ss = 0; ss < NSUB; ++ss) s += h[(ss << 8) | t];
        if (MODE == 0) {
            out[blockIdx.x * NBINS + t] = s;
        } else {
            if (s) atomicAdd(&out[t], s);
        }
    }
}

// ---------------------------------------------------------------------------
// Kernel 2: threshold + binarize, no handshake. Prologue: every block
// redundantly reduces the B partial rows (coalesced L2-resident loads,
// thread (bin,q) sums its quarter) and wave 0 runs the exact scan + fp64
// argmax; LDS-broadcast. Then binarize: out image lives at out[1..HW], so
// aligned out-chunk out[4c..4c+3] needs pixels [4c-1..4c+2], loaded as a
// dword-aligned dwordx4 (L3-hit) — no shuffles, no divergence; 16 B-aligned
// nontemporal stores. Chunk 0 writes out[0] = thresh; thread i0==0 the tail.
// ---------------------------------------------------------------------------
__global__ __launch_bounds__(BLK, 8) void otsu_bin_k(const int* __restrict__ img,
                                                     int* __restrict__ out,
                                                     const unsigned* __restrict__ partials,
                                                     int B) {
    __shared__ unsigned red[4][NBINS];
    __shared__ unsigned cnt[NBINS];
    __shared__ int s_thresh;

    const int t = threadIdx.x;
    const int bin = t & 255;
    const int q = t >> 8;
    const int BQ = (B + 3) / 4;
    {
        int r = q * BQ;
        const int e = min((q + 1) * BQ, B);
        unsigned s = 0;
        for (; r + 16 <= e; r += 16) {
#pragma unroll
            for (int k = 0; k < 16; ++k) s += partials[(r + k) * NBINS + bin];
        }
        for (; r < e; ++r) s += partials[r * NBINS + bin];
        red[q][bin] = s;
    }
    __syncthreads();
    if (t < NBINS)
        cnt[bin] = red[0][bin] + red[1][bin] + red[2][bin] + red[3][bin];
    __syncthreads();
    if (t < 64) {
        int bt = otsu_scan64(cnt, t);
        if (t == 0) s_thresh = bt;
    }
    __syncthreads();
    const int thresh = s_thresh;

    const int wave = t >> 6, lane = t & 63;
    const int i0 = blockIdx.x * (BLK * BBATCH) + wave * (64 * BBATCH) + lane;
#pragma unroll
    for (int k = 0; k < BBATCH; ++k) {
        const int c = i0 + k * 64;
        int4a v = *(const int4a*)(img + (c ? 4 * c - 1 : 0));  // pixels 4c-1..4c+2
        int4n o;
        o.x = (v.x <= thresh) ? 0 : 256;
        o.y = (v.y <= thresh) ? 0 : 256;
        o.z = (v.z <= thresh) ? 0 : 256;
        o.w = (v.w <= thresh) ? 0 : 256;
        if (c == 0) { o.w = o.z; o.z = o.y; o.y = o.x; o.x = thresh; }
        __builtin_nontemporal_store(o, (int4n*)out + c);
    }
    if (i0 == 0)
        out[HW_TOTAL] = (img[HW_TOTAL - 1] <= thresh) ? 0 : 256;
}

extern "C" void kernel_launch(void* const* d_in, const int* in_sizes, int n_in,
                              void* d_out, int out_size, void* d_ws, size_t ws_size,
                              hipStream_t stream) {
    const int* img = (const int*)d_in[0];
    int* out = (int*)d_out;
    unsigned* hist_buf = (unsigned*)((char*)d_ws + 256);

    if (ws_size >= (size_t)WS_NEED) {
        // 2-node path: hist -> (thresh+bin). No atomics, no memset, no flags.
        otsu_hist_k<0><<<HGRID, BLK, 0, stream>>>((const int4*)img, hist_buf);
        otsu_bin_k<<<BGRID, BLK, 0, stream>>>(img, out, hist_buf, HGRID);
    } else {
        // fallback: atomic flush into a single 256-bin histogram
        (void)hipMemsetAsync(hist_buf, 0, NBINS * sizeof(unsigned), stream);
        otsu_hist_k<1><<<HGRID, BLK, 0, stream>>>((const int4*)img, hist_buf);
        otsu_bin_k<<<BGRID, BLK, 0, stream>>>(img, out, hist_buf, 1);
    }
}